// Round 8
// baseline (457.703 us; speedup 1.0000x reference)
//
#include <hip/hip_runtime.h>
#include <cstdint>

typedef unsigned short u16;
typedef __attribute__((ext_vector_type(8))) short bf16x8;
typedef __attribute__((ext_vector_type(4))) float f32x4;
typedef __attribute__((ext_vector_type(4))) unsigned short u16x4;

#define AS_G __attribute__((address_space(1)))
#define AS_L __attribute__((address_space(3)))

__device__ __forceinline__ void gl_lds16(const u16* g, u16* l) {
  // async global->LDS, 16B/lane; LDS dest = wave-uniform base + lane*16
  __builtin_amdgcn_global_load_lds((const AS_G unsigned int*)g, (AS_L unsigned int*)l, 16, 0, 0);
}
__device__ __forceinline__ float bf2f(u16 u) {
  union { unsigned int i; float f; } v; v.i = ((unsigned int)u) << 16; return v.f;
}
__device__ __forceinline__ u16 f2bf(float f) {
  union { float f; unsigned int i; } v; v.f = f;
  unsigned int x = v.i;
  return (u16)((x + 0x7fffu + ((x >> 16) & 1u)) >> 16);  // RNE
}

// ---------------- fp32 -> bf16 convert of q/k/v ----------------
__global__ __launch_bounds__(256) void convert_kernel(
    const float* __restrict__ q, const float* __restrict__ k, const float* __restrict__ v,
    u16* __restrict__ qb, u16* __restrict__ kb, u16* __restrict__ vb)
{
  const int id = blockIdx.y;
  const float* s = (id == 0) ? q : (id == 1) ? k : v;
  u16* d = (id == 0) ? qb : (id == 1) ? kb : vb;
  const int o = (blockIdx.x * 256 + threadIdx.x) * 4;
  const f32x4 x = *(const f32x4*)(s + o);
  u16x4 y;
#pragma unroll
  for (int i = 0; i < 4; ++i) y[i] = f2bf(x[i]);
  *(u16x4*)(d + o) = y;
}

// ---------------- weight pre-transpose (fp32 src -> bf16 dst) ----------------
__global__ __launch_bounds__(256) void transpose_kernel(
    const float* __restrict__ s0, const float* __restrict__ s1, const float* __restrict__ s2,
    const float* __restrict__ s3, const float* __restrict__ s4, u16* __restrict__ wdst)
{
  const int id = blockIdx.y;
  const float* src; u16* dst; int rb, total;
  switch (id) {
    case 0:  src = s0; dst = wdst;           rb = 8;  total = 524288; break;
    case 1:  src = s1; dst = wdst + 524288;  rb = 8;  total = 524288; break;
    case 2:  src = s2; dst = wdst + 1048576; rb = 8;  total = 524288; break;
    case 3:  src = s3; dst = wdst + 1572864; rb = 11; total = 524288; break;
    default: src = s4; dst = wdst + 2097152; rb = 8;  total = 65536;  break;
  }
  const int o = blockIdx.x * 256 + threadIdx.x;
  if (o >= total) return;
  const int C_ = total >> rb;
  const int c = o >> rb, r = o & ((1 << rb) - 1);
  dst[o] = f2bf(src[r * C_ + c]);
}

// ---------------- fused QKV projection: C = gather(x) @ W + b ----------------
// 128x128 tile, 4 waves. NO LDS staging in the K-loop: fragments loaded
// directly from global (L2-resident; A/B fragment reuse within a block is only
// 2x, not worth the barrier drains). Zero __syncthreads until the epilogue.
// Epilogue: LDS re-layout (pad +8) -> 16B/lane coalesced stores.
__global__ __launch_bounds__(256) void proj_kernel(
    const u16* __restrict__ qb, const u16* __restrict__ kb, const u16* __restrict__ vb,
    const u16* __restrict__ wts, const float* __restrict__ bq, const float* __restrict__ bk,
    const float* __restrict__ bv, u16* __restrict__ Pq, u16* __restrict__ Pk,
    u16* __restrict__ Pv, int zoff)
{
  __shared__ u16 lds[17408];            // epilogue re-layout only (128 x 136)
  const int t = threadIdx.x;
  const int w = t >> 6, lane = t & 63, quad = lane >> 4, lc = lane & 15;
  const int wy = w >> 1, wx = w & 1;
  const int tn = blockIdx.x, bb = blockIdx.y, z = blockIdx.z + zoff;
  const int b = bb / 15, n = bb % 15;
  const u16* A0 = ((z == 0) ? qb : (z == 1) ? kb : vb) + (b * 1024 + n * 64) * 256;
  const u16* BT = wts + z * 524288 + tn * 128 * 256;

  // per-lane fragment base pointers (row-strided direct loads)
  const u16* Abase = A0 + (wy * 64 + lc) * 256 + quad * 8;
  const u16* Bbase = BT + (wx * 64 + lc) * 256 + quad * 8;

  const f32x4 fz = {0.f, 0.f, 0.f, 0.f};
  f32x4 acc[4][4];
#pragma unroll
  for (int i = 0; i < 4; ++i)
#pragma unroll
    for (int j = 0; j < 4; ++j) acc[i][j] = fz;

#pragma unroll 2
  for (int kc = 0; kc < 8; ++kc) {
    bf16x8 af[4], bfg[4];
#pragma unroll
    for (int mi = 0; mi < 4; ++mi)
      af[mi] = *(const bf16x8*)(Abase + mi * 16 * 256 + kc * 32);
#pragma unroll
    for (int ni = 0; ni < 4; ++ni)
      bfg[ni] = *(const bf16x8*)(Bbase + ni * 16 * 256 + kc * 32);
#pragma unroll
    for (int mi = 0; mi < 4; ++mi)
#pragma unroll
      for (int ni = 0; ni < 4; ++ni)
        acc[mi][ni] = __builtin_amdgcn_mfma_f32_16x16x32_bf16(af[mi], bfg[ni], acc[mi][ni], 0, 0, 0);
  }

  const float* bias = (z == 0) ? bq : (z == 1) ? bk : bv;
  u16* P = ((z == 0) ? Pq : (z == 1) ? Pk : Pv) + bb * 262144;

#pragma unroll
  for (int mi = 0; mi < 4; ++mi)
#pragma unroll
    for (int ni = 0; ni < 4; ++ni) {
      const int col = wx * 64 + ni * 16 + lc;
      const float bi = bias[tn * 128 + col];
#pragma unroll
      for (int r = 0; r < 4; ++r) {
        const int row = wy * 64 + mi * 16 + quad * 4 + r;
        lds[row * 136 + col] = f2bf(acc[mi][ni][r] + bi);
      }
    }
  __syncthreads();
#pragma unroll
  for (int p = 0; p < 8; ++p) {          // 256B-contiguous row segments, 16B/lane
    const int e = p * 2048 + t * 8;
    const int row = e >> 7, col0 = e & 127;
    *(bf16x8*)(P + row * 2048 + tn * 128 + col0) = *(const bf16x8*)&lds[row * 136 + col0];
  }
}

// ---------------- Pv -> VT batched transpose (coalesced both sides) ----------------
__global__ __launch_bounds__(256) void vtrans_kernel(
    const u16* __restrict__ Pv, u16* __restrict__ VT)
{
  __shared__ u16 lT[4096];
  const int t = threadIdx.x;
  const int tile = blockIdx.x;          // 0..7
  const int sh = blockIdx.y;            // bb*8 + h
  const int q0 = (tile & 1) * 64, d0 = (tile >> 1) * 64;
  const u16* src = Pv + sh * 32768;     // head slab [q=128][d=256] (raw-reshape view)
  u16* dst = VT + sh * 32768;           // [d=256][q=128]
#pragma unroll
  for (int it = 0; it < 2; ++it) {
    const int e = it * 2048 + t * 8;
    const int lq = e >> 6, ld0 = e & 63;
    const bf16x8 v = *(const bf16x8*)(src + (q0 + lq) * 256 + d0 + ld0);
    const int kb = ((ld0 >> 3) + lq + (lq >> 3)) & 7;
    *(bf16x8*)&lT[lq * 64 + kb * 8] = v;
  }
  __syncthreads();
#pragma unroll
  for (int it = 0; it < 2; ++it) {
    const int e = it * 2048 + t * 8;
    const int ld = e >> 6, lq0 = e & 63;
    bf16x8 v;
#pragma unroll
    for (int i = 0; i < 8; ++i) {
      const int lq = lq0 + i;
      const int kb = ((ld >> 3) + lq + (lq >> 3)) & 7;
      v[i] = (short)lT[lq * 64 + kb * 8 + (ld & 7)];
    }
    *(bf16x8*)(dst + (d0 + ld) * 128 + q0 + lq0) = v;
  }
}

// ---------------- attention per (block, head) ----------------
__global__ __launch_bounds__(512) void attn_kernel(
    const u16* __restrict__ Pq, const u16* __restrict__ Pk,
    const u16* __restrict__ VT, u16* Obuf)
{
  __shared__ u16 lKV[16384];
  __shared__ u16 lP[16384];
  const int t = threadIdx.x;
  const int w = t >> 6, lane = t & 63, quad = lane >> 4, lc = lane & 15;
  const int h = blockIdx.x, bb = blockIdx.y;
  const int m0 = w * 16;
  const u16* Qb = Pq + bb * 262144 + h * 32768;
  const u16* Kb = Pk + bb * 262144 + h * 32768;
  const u16* Vb = VT + (bb * 8 + h) * 32768;
  const f32x4 fz = {0.f, 0.f, 0.f, 0.f};

  bf16x8 aq[8];
#pragma unroll
  for (int kc = 0; kc < 8; ++kc)
    aq[kc] = *(const bf16x8*)(Qb + (m0 + lc) * 256 + kc * 32 + quad * 8);

  f32x4 s[8];
  for (int hk = 0; hk < 2; ++hk) {
    __syncthreads();
#pragma unroll
    for (int jj = 0; jj < 4; ++jj)
      gl_lds16(Kb + (hk * 64 + lane) * 256 + w * 32 + jj * 8, &lKV[w * 2048 + jj * 512]);
    __syncthreads();
#pragma unroll
    for (int ntl = 0; ntl < 4; ++ntl) {
      const int nt = hk * 4 + ntl;
      s[nt] = fz;
#pragma unroll
      for (int kc = 0; kc < 8; ++kc) {
        const bf16x8 bfr = *(const bf16x8*)&lKV[kc * 2048 + quad * 512 + (ntl * 16 + lc) * 8];
        s[nt] = __builtin_amdgcn_mfma_f32_16x16x32_bf16(aq[kc], bfr, s[nt], 0, 0, 0);
      }
    }
  }

  const float scale = 0.0625f;
#pragma unroll
  for (int r = 0; r < 4; ++r) {
    float mx = -3.0e38f;
#pragma unroll
    for (int nt = 0; nt < 8; ++nt) mx = fmaxf(mx, s[nt][r]);
    mx = fmaxf(mx, __shfl_xor(mx, 1)); mx = fmaxf(mx, __shfl_xor(mx, 2));
    mx = fmaxf(mx, __shfl_xor(mx, 4)); mx = fmaxf(mx, __shfl_xor(mx, 8));
    mx *= scale;
    float sm = 0.0f;
#pragma unroll
    for (int nt = 0; nt < 8; ++nt) {
      const float e = __expf(s[nt][r] * scale - mx);
      s[nt][r] = e; sm += e;
    }
    sm += __shfl_xor(sm, 1); sm += __shfl_xor(sm, 2);
    sm += __shfl_xor(sm, 4); sm += __shfl_xor(sm, 8);
    const float inv = 1.0f / sm;
    const int q = m0 + quad * 4 + r;
#pragma unroll
    for (int nt = 0; nt < 8; ++nt) {
      const int k = nt * 16 + lc;
      lP[(k >> 5) * 4096 + ((k >> 3) & 3) * 1024 + q * 8 + (k & 7)] = f2bf(s[nt][r] * inv);
    }
  }
  __syncthreads();

  bf16x8 ap[4];
#pragma unroll
  for (int kc2 = 0; kc2 < 4; ++kc2)
    ap[kc2] = *(const bf16x8*)&lP[kc2 * 4096 + quad * 1024 + (m0 + lc) * 8];

  f32x4 o[16];
#pragma unroll
  for (int nt = 0; nt < 16; ++nt) o[nt] = fz;

  for (int hk = 0; hk < 2; ++hk) {
    if (hk) __syncthreads();
#pragma unroll
    for (int jj = 0; jj < 4; ++jj) {
      const int i = w * 4 + jj;
      const int kc2l = i >> 4, cb = (i >> 2) & 3, db = (i & 3) * 64;
      gl_lds16(Vb + (db + lane) * 128 + (hk * 2 + kc2l) * 32 + cb * 8,
               &lKV[kc2l * 8192 + cb * 2048 + db * 8]);
    }
    __syncthreads();
#pragma unroll
    for (int nt = 0; nt < 16; ++nt)
#pragma unroll
      for (int kc2l = 0; kc2l < 2; ++kc2l) {
        const bf16x8 bfr = *(const bf16x8*)&lKV[kc2l * 8192 + quad * 2048 + (nt * 16 + lc) * 8];
        o[nt] = __builtin_amdgcn_mfma_f32_16x16x32_bf16(ap[hk * 2 + kc2l], bfr, o[nt], 0, 0, 0);
      }
  }

  u16* Ob = Obuf + bb * 262144 + h * 32768;   // == Qb slab; own rows already in aq
#pragma unroll
  for (int nt = 0; nt < 16; ++nt)
#pragma unroll
    for (int r = 0; r < 4; ++r) {
      const int q = m0 + quad * 4 + r;
      Ob[q * 256 + nt * 16 + lc] = f2bf(o[nt][r]);
    }
}

// ---------------- 64x128-tile GEMM (4 waves x 32 cols), optional split-K ----------------
// mode 0: raw fp32 partial store to out + kz*3932160 (Wo split-K path).
// mode 1: bias + bf16 residual epilogue -> fp32 out (FF path, gridDim.z == 1).
__global__ __launch_bounds__(256) void gemm64_kernel(
    const u16* __restrict__ A, const u16* __restrict__ BT, const float* __restrict__ bias,
    const u16* __restrict__ residb, float* __restrict__ out, int Ktot, int lda, int mode)
{
  __shared__ u16 lA[2048];    // [kb 0..3][row 0..63][8]
  __shared__ u16 lB[4096];    // [kb 0..3][half 0..1][col 0..63][8]
  const int t = threadIdx.x;
  const int w = t >> 6, lane = t & 63, quad = lane >> 4, lc = lane & 15;
  const int tn = blockIdx.x, bb = blockIdx.y, kz = blockIdx.z;
  const int kslice = Ktot / gridDim.z;
  const int k0 = kz * kslice;
  const u16* A0 = A + bb * 64 * lda + k0;
  const u16* BT0 = BT + tn * 128 * Ktot + k0;

  const f32x4 fz = {0.f, 0.f, 0.f, 0.f};
  f32x4 acc[4][2];
#pragma unroll
  for (int i = 0; i < 4; ++i) { acc[i][0] = fz; acc[i][1] = fz; }

  const int nck = kslice >> 5;
  for (int ck = 0; ck < nck; ++ck) {
    __syncthreads();
    const int koff = ck * 32 + w * 8;
    gl_lds16(A0 + lane * lda + koff,          &lA[w * 512]);
    gl_lds16(BT0 + lane * Ktot + koff,        &lB[w * 1024]);
    gl_lds16(BT0 + (64 + lane) * Ktot + koff, &lB[w * 1024 + 512]);
    __syncthreads();
    bf16x8 af[4], bfg[2];
#pragma unroll
    for (int mi = 0; mi < 4; ++mi)
      af[mi] = *(const bf16x8*)&lA[quad * 512 + (mi * 16 + lc) * 8];
#pragma unroll
    for (int ni = 0; ni < 2; ++ni) {
      const int cl = w * 32 + ni * 16 + lc;      // 0..127 within tile
      bfg[ni] = *(const bf16x8*)&lB[quad * 1024 + (cl >> 6) * 512 + (cl & 63) * 8];
    }
#pragma unroll
    for (int mi = 0; mi < 4; ++mi)
#pragma unroll
      for (int ni = 0; ni < 2; ++ni)
        acc[mi][ni] = __builtin_amdgcn_mfma_f32_16x16x32_bf16(af[mi], bfg[ni], acc[mi][ni], 0, 0, 0);
  }

  if (mode == 0) {
    float* O = out + kz * 3932160 + bb * 64 * 256;
#pragma unroll
    for (int mi = 0; mi < 4; ++mi)
#pragma unroll
      for (int ni = 0; ni < 2; ++ni) {
        const int cg = tn * 128 + w * 32 + ni * 16 + lc;
#pragma unroll
        for (int r = 0; r < 4; ++r)
          O[(mi * 16 + quad * 4 + r) * 256 + cg] = acc[mi][ni][r];
      }
  } else {
#pragma unroll
    for (int mi = 0; mi < 4; ++mi)
#pragma unroll
      for (int ni = 0; ni < 2; ++ni) {
        const int cg = tn * 128 + w * 32 + ni * 16 + lc;
        const float bi = bias[cg];
#pragma unroll
        for (int r = 0; r < 4; ++r) {
          const int rl = mi * 16 + quad * 4 + r;
          const float res = bf2f(residb[(bb * 64 + rl) * 256 + cg]);
          out[(bb * 64 + rl) * 256 + cg] = acc[mi][ni][r] + bi + res;
        }
      }
  }
}

// ---------------- split-K reduce: tmp1 = sum(4 partials) + bias + fp32 value resid ----------------
// 3840 blocks x 256 thr x 4 elems == 3,932,160 floats (15360 rows x 256 cols).
__global__ __launch_bounds__(256) void reduce_kernel(
    const float* __restrict__ part, const float* __restrict__ bias,
    const float* __restrict__ value, float* __restrict__ out)
{
  const int e = (blockIdx.x * 256 + threadIdx.x) * 4;
  const int row = e >> 8, col = e & 255;
  const int bb = row >> 7, rl = row & 127, b = bb / 15, n = bb % 15;
  f32x4 s = *(const f32x4*)(part + e);
#pragma unroll
  for (int p = 1; p < 4; ++p) {
    const f32x4 v = *(const f32x4*)(part + p * 3932160 + e);
#pragma unroll
    for (int i = 0; i < 4; ++i) s[i] += v[i];
  }
  const f32x4 bi = *(const f32x4*)(bias + col);
  const f32x4 rv = *(const f32x4*)(value + (b * 1024 + n * 64 + rl) * 256 + col);
#pragma unroll
  for (int i = 0; i < 4; ++i) s[i] += bi[i] + rv[i];
  *(f32x4*)(out + e) = s;
}

// ---------------- layernorm (one wave per 256-wide row) ----------------
__global__ __launch_bounds__(256) void ln_kernel(
    const float* __restrict__ src, const float* __restrict__ gam, const float* __restrict__ bet,
    u16* __restrict__ dstb, float* __restrict__ dstf, int mode)
{
  const int t = threadIdx.x, w = t >> 6, lane = t & 63;
  const int row = blockIdx.x * 4 + w;
  const f32x4 v = *(const f32x4*)(src + row * 256 + lane * 4);
  float sum = v[0] + v[1] + v[2] + v[3];
  float sq = v[0] * v[0] + v[1] * v[1] + v[2] * v[2] + v[3] * v[3];
#pragma unroll
  for (int m = 1; m < 64; m <<= 1) { sum += __shfl_xor(sum, m); sq += __shfl_xor(sq, m); }
  const float mean = sum * (1.0f / 256.0f);
  const float rs = rsqrtf(sq * (1.0f / 256.0f) - mean * mean + 1e-5f);
  const f32x4 g4 = *(const f32x4*)(gam + lane * 4);
  const f32x4 b4 = *(const f32x4*)(bet + lane * 4);
  f32x4 o;
#pragma unroll
  for (int i = 0; i < 4; ++i)
    o[i] = (v[i] - mean) * rs * g4[i] + b4[i];
  if (mode == 0) {
    u16x4 ob;
#pragma unroll
    for (int i = 0; i < 4; ++i) ob[i] = f2bf(o[i]);
    *(u16x4*)(dstb + row * 256 + lane * 4) = ob;
  } else {
    const int bbq = row >> 7, r = row & 127, b = bbq / 15, n = bbq % 15;
    const bool valid = (n == 0) ? (r < 96) : ((n == 14) ? (r >= 32) : (r >= 32 && r < 96));
    if (valid)
      *(f32x4*)(dstf + ((b << 10) + n * 64 + r) * 256 + lane * 4) = o;
  }
}

extern "C" void kernel_launch(void* const* d_in, const int* in_sizes, int n_in,
                              void* d_out, int out_size, void* d_ws, size_t ws_size,
                              hipStream_t stream) {
  (void)in_sizes; (void)n_in; (void)out_size; (void)ws_size;
  const float* query = (const float*)d_in[0];
  const float* key   = (const float*)d_in[1];
  const float* value = (const float*)d_in[2];
  const float* Wq  = (const float*)d_in[3];
  const float* bq  = (const float*)d_in[4];
  const float* Wk  = (const float*)d_in[5];
  const float* bk  = (const float*)d_in[6];
  const float* Wv  = (const float*)d_in[7];
  const float* bv  = (const float*)d_in[8];
  const float* Wo  = (const float*)d_in[9];
  const float* bo  = (const float*)d_in[10];
  const float* g1  = (const float*)d_in[11];
  const float* b1  = (const float*)d_in[12];
  const float* Wff = (const float*)d_in[13];
  const float* bff = (const float*)d_in[14];
  const float* g2  = (const float*)d_in[15];
  const float* b2  = (const float*)d_in[16];

  // Phase-ordered layout, peak 205,651,968 B (round-2 validated footprint):
  u16* ws   = (u16*)d_ws;
  u16* WT   = ws;                    // 2,162,688 u16 (WqT,WkT,WvT,WoT,WffT)
  u16* qb   = ws + 2162688;          // 2,097,152 u16 each
  u16* kb   = qb + 2097152;
  u16* vb   = kb + 2097152;
  u16* S1   = vb + 2097152;          // slab 31,457,280 u16: Pv -> Pq -> Obuf
  u16* S2   = S1 + 31457280;         // slab: VT -> Wo split-K partials (4 x 3,932,160 f32) -> tmp2
  u16* S3   = S2 + 31457280;         // slab: Pk -> tmp1/xbuf
  float* part = (float*)S2;          // 4 x 3,932,160 f32 == exactly one slab
  float* tmp1 = (float*)S3;          // 3,932,160 f32 (Pk dead after attn)
  u16* xbuf   = S3 + 7864320;
  float* tmp2 = (float*)S2;          // (partials dead after reduce)

  convert_kernel<<<dim3(2048, 3), 256, 0, stream>>>(query, key, value, qb, kb, vb);
  transpose_kernel<<<dim3(2048, 5), 256, 0, stream>>>(Wq, Wk, Wv, Wo, Wff, WT);
  // V projection first -> S1, transpose into S2, then Q/K reuse S1/S3.
  proj_kernel<<<dim3(16, 120, 1), 256, 0, stream>>>(qb, kb, vb, WT, bq, bk, bv, S1, S3, S1, 2);
  vtrans_kernel<<<dim3(8, 960), 256, 0, stream>>>(S1, S2);
  proj_kernel<<<dim3(16, 120, 2), 256, 0, stream>>>(qb, kb, vb, WT, bq, bk, bv, S1, S3, S1, 0);
  attn_kernel<<<dim3(8, 120), 512, 0, stream>>>(S1, S3, S2, S1);
  // Wo GEMM: 64-row tiles, split-K=4 -> partials in S2, then reduce (+bias+value resid).
  gemm64_kernel<<<dim3(2, 240, 4), 256, 0, stream>>>(S1, WT + 1572864, nullptr, nullptr, part, 2048, 2048, 0);
  reduce_kernel<<<3840, 256, 0, stream>>>(part, bo, value, tmp1);
  ln_kernel<<<3840, 256, 0, stream>>>(tmp1, g1, b1, xbuf, nullptr, 0);
  // FF GEMM: 64-row tiles, fused bias + residual epilogue.
  gemm64_kernel<<<dim3(2, 240, 1), 256, 0, stream>>>(xbuf, WT + 2097152, bff, xbuf, tmp2, 256, 256, 1);
  ln_kernel<<<3840, 256, 0, stream>>>(tmp2, g2, b2, nullptr, (float*)d_out, 1);
}

// Round 9
// 455.969 us; speedup vs baseline: 1.0038x; 1.0038x over previous
//
#include <hip/hip_runtime.h>
#include <cstdint>

typedef unsigned short u16;
typedef __attribute__((ext_vector_type(8))) short bf16x8;
typedef __attribute__((ext_vector_type(4))) float f32x4;
typedef __attribute__((ext_vector_type(4))) unsigned short u16x4;

#define AS_G __attribute__((address_space(1)))
#define AS_L __attribute__((address_space(3)))

__device__ __forceinline__ void gl_lds16(const u16* g, u16* l) {
  // async global->LDS, 16B/lane; LDS dest = wave-uniform base + lane*16
  __builtin_amdgcn_global_load_lds((const AS_G unsigned int*)g, (AS_L unsigned int*)l, 16, 0, 0);
}
__device__ __forceinline__ float bf2f(u16 u) {
  union { unsigned int i; float f; } v; v.i = ((unsigned int)u) << 16; return v.f;
}
__device__ __forceinline__ u16 f2bf(float f) {
  union { float f; unsigned int i; } v; v.f = f;
  unsigned int x = v.i;
  return (u16)((x + 0x7fffu + ((x >> 16) & 1u)) >> 16);  // RNE
}

// ---------------- fp32 -> bf16 convert of q/k/v ----------------
__global__ __launch_bounds__(256) void convert_kernel(
    const float* __restrict__ q, const float* __restrict__ k, const float* __restrict__ v,
    u16* __restrict__ qb, u16* __restrict__ kb, u16* __restrict__ vb)
{
  const int id = blockIdx.y;
  const float* s = (id == 0) ? q : (id == 1) ? k : v;
  u16* d = (id == 0) ? qb : (id == 1) ? kb : vb;
  const int o = (blockIdx.x * 256 + threadIdx.x) * 4;
  const f32x4 x = *(const f32x4*)(s + o);
  u16x4 y;
#pragma unroll
  for (int i = 0; i < 4; ++i) y[i] = f2bf(x[i]);
  *(u16x4*)(d + o) = y;
}

// ---------------- weight pre-transpose (fp32 src -> bf16 dst) ----------------
__global__ __launch_bounds__(256) void transpose_kernel(
    const float* __restrict__ s0, const float* __restrict__ s1, const float* __restrict__ s2,
    const float* __restrict__ s3, const float* __restrict__ s4, u16* __restrict__ wdst)
{
  const int id = blockIdx.y;
  const float* src; u16* dst; int rb, total;
  switch (id) {
    case 0:  src = s0; dst = wdst;           rb = 8;  total = 524288; break;
    case 1:  src = s1; dst = wdst + 524288;  rb = 8;  total = 524288; break;
    case 2:  src = s2; dst = wdst + 1048576; rb = 8;  total = 524288; break;
    case 3:  src = s3; dst = wdst + 1572864; rb = 11; total = 524288; break;
    default: src = s4; dst = wdst + 2097152; rb = 8;  total = 65536;  break;
  }
  const int o = blockIdx.x * 256 + threadIdx.x;
  if (o >= total) return;
  const int C_ = total >> rb;
  const int c = o >> rb, r = o & ((1 << rb) - 1);
  dst[o] = f2bf(src[r * C_ + c]);
}

// ---------------- fused QKV projection: C = gather(x) @ W + b ----------------
// 128x128 tile, 4 waves. B (128 cols x K=256 = 64KB) staged to LDS ONCE, then
// the whole K-loop runs with ZERO barriers: B fragments via ds_read_b128,
// A fragments streamed directly from global (L2-hot, fully unrolled so loads
// hoist under MFMA). Epilogue reuses the B LDS region (pad +8) for coalesced
// 16B/lane stores.
__global__ __launch_bounds__(256) void proj_kernel(
    const u16* __restrict__ qb, const u16* __restrict__ kb, const u16* __restrict__ vb,
    const u16* __restrict__ wts, const float* __restrict__ bq, const float* __restrict__ bk,
    const float* __restrict__ bv, u16* __restrict__ Pq, u16* __restrict__ Pk,
    u16* __restrict__ Pv, int zoff)
{
  __shared__ u16 lds[32768];            // B: [blk 0..31][col 0..127][8]; epilogue reuse
  const int t = threadIdx.x;
  const int w = t >> 6, lane = t & 63, quad = lane >> 4, lc = lane & 15;
  const int wy = w >> 1, wx = w & 1;
  const int tn = blockIdx.x, bb = blockIdx.y, z = blockIdx.z + zoff;
  const int b = bb / 15, n = bb % 15;
  const u16* A0 = ((z == 0) ? qb : (z == 1) ? kb : vb) + (b * 1024 + n * 64) * 256;
  const u16* BT = wts + z * 524288 + tn * 128 * 256;

  // Stage whole B tile once: 16 issues/wave, 1KB each.
#pragma unroll
  for (int i = 0; i < 16; ++i) {
    const int idx = w * 16 + i;          // 0..63
    const int blk = idx >> 1, half = idx & 1;
    gl_lds16(BT + (half * 64 + lane) * 256 + blk * 8,
             &lds[blk * 1024 + half * 512]);
  }

  const f32x4 fz = {0.f, 0.f, 0.f, 0.f};
  f32x4 acc[4][4];
#pragma unroll
  for (int i = 0; i < 4; ++i)
#pragma unroll
    for (int j = 0; j < 4; ++j) acc[i][j] = fz;

  const u16* Abase = A0 + (wy * 64 + lc) * 256 + quad * 8;
  __syncthreads();                      // B resident; K-loop is barrier-free

#pragma unroll
  for (int kc = 0; kc < 8; ++kc) {
    bf16x8 af[4], bfg[4];
#pragma unroll
    for (int mi = 0; mi < 4; ++mi)
      af[mi] = *(const bf16x8*)(Abase + mi * 16 * 256 + kc * 32);
#pragma unroll
    for (int ni = 0; ni < 4; ++ni)
      bfg[ni] = *(const bf16x8*)&lds[(kc * 4 + quad) * 1024 + (wx * 64 + ni * 16 + lc) * 8];
#pragma unroll
    for (int mi = 0; mi < 4; ++mi)
#pragma unroll
      for (int ni = 0; ni < 4; ++ni)
        acc[mi][ni] = __builtin_amdgcn_mfma_f32_16x16x32_bf16(af[mi], bfg[ni], acc[mi][ni], 0, 0, 0);
  }

  const float* bias = (z == 0) ? bq : (z == 1) ? bk : bv;
  u16* P = ((z == 0) ? Pq : (z == 1) ? Pk : Pv) + bb * 262144;

  __syncthreads();                       // all B reads done; reuse LDS for epilogue
#pragma unroll
  for (int mi = 0; mi < 4; ++mi)
#pragma unroll
    for (int ni = 0; ni < 4; ++ni) {
      const int col = wx * 64 + ni * 16 + lc;
      const float bi = bias[tn * 128 + col];
#pragma unroll
      for (int r = 0; r < 4; ++r) {
        const int row = wy * 64 + mi * 16 + quad * 4 + r;
        lds[row * 136 + col] = f2bf(acc[mi][ni][r] + bi);
      }
    }
  __syncthreads();
#pragma unroll
  for (int p = 0; p < 8; ++p) {          // 256B-contiguous row segments, 16B/lane
    const int e = p * 2048 + t * 8;
    const int row = e >> 7, col0 = e & 127;
    *(bf16x8*)(P + row * 2048 + tn * 128 + col0) = *(const bf16x8*)&lds[row * 136 + col0];
  }
}

// ---------------- Pv -> VT batched transpose (coalesced both sides) ----------------
__global__ __launch_bounds__(256) void vtrans_kernel(
    const u16* __restrict__ Pv, u16* __restrict__ VT)
{
  __shared__ u16 lT[4096];
  const int t = threadIdx.x;
  const int tile = blockIdx.x;          // 0..7
  const int sh = blockIdx.y;            // bb*8 + h
  const int q0 = (tile & 1) * 64, d0 = (tile >> 1) * 64;
  const u16* src = Pv + sh * 32768;     // head slab [q=128][d=256] (raw-reshape view)
  u16* dst = VT + sh * 32768;           // [d=256][q=128]
#pragma unroll
  for (int it = 0; it < 2; ++it) {
    const int e = it * 2048 + t * 8;
    const int lq = e >> 6, ld0 = e & 63;
    const bf16x8 v = *(const bf16x8*)(src + (q0 + lq) * 256 + d0 + ld0);
    const int kb = ((ld0 >> 3) + lq + (lq >> 3)) & 7;
    *(bf16x8*)&lT[lq * 64 + kb * 8] = v;
  }
  __syncthreads();
#pragma unroll
  for (int it = 0; it < 2; ++it) {
    const int e = it * 2048 + t * 8;
    const int ld = e >> 6, lq0 = e & 63;
    bf16x8 v;
#pragma unroll
    for (int i = 0; i < 8; ++i) {
      const int lq = lq0 + i;
      const int kb = ((ld >> 3) + lq + (lq >> 3)) & 7;
      v[i] = (short)lT[lq * 64 + kb * 8 + (ld & 7)];
    }
    *(bf16x8*)(dst + (d0 + ld) * 128 + q0 + lq0) = v;
  }
}

// ---------------- attention per (block, head) ----------------
__global__ __launch_bounds__(512) void attn_kernel(
    const u16* __restrict__ Pq, const u16* __restrict__ Pk,
    const u16* __restrict__ VT, u16* Obuf)
{
  __shared__ u16 lKV[16384];
  __shared__ u16 lP[16384];
  const int t = threadIdx.x;
  const int w = t >> 6, lane = t & 63, quad = lane >> 4, lc = lane & 15;
  const int h = blockIdx.x, bb = blockIdx.y;
  const int m0 = w * 16;
  const u16* Qb = Pq + bb * 262144 + h * 32768;
  const u16* Kb = Pk + bb * 262144 + h * 32768;
  const u16* Vb = VT + (bb * 8 + h) * 32768;
  const f32x4 fz = {0.f, 0.f, 0.f, 0.f};

  bf16x8 aq[8];
#pragma unroll
  for (int kc = 0; kc < 8; ++kc)
    aq[kc] = *(const bf16x8*)(Qb + (m0 + lc) * 256 + kc * 32 + quad * 8);

  f32x4 s[8];
  for (int hk = 0; hk < 2; ++hk) {
    __syncthreads();
#pragma unroll
    for (int jj = 0; jj < 4; ++jj)
      gl_lds16(Kb + (hk * 64 + lane) * 256 + w * 32 + jj * 8, &lKV[w * 2048 + jj * 512]);
    __syncthreads();
#pragma unroll
    for (int ntl = 0; ntl < 4; ++ntl) {
      const int nt = hk * 4 + ntl;
      s[nt] = fz;
#pragma unroll
      for (int kc = 0; kc < 8; ++kc) {
        const bf16x8 bfr = *(const bf16x8*)&lKV[kc * 2048 + quad * 512 + (ntl * 16 + lc) * 8];
        s[nt] = __builtin_amdgcn_mfma_f32_16x16x32_bf16(aq[kc], bfr, s[nt], 0, 0, 0);
      }
    }
  }

  const float scale = 0.0625f;
#pragma unroll
  for (int r = 0; r < 4; ++r) {
    float mx = -3.0e38f;
#pragma unroll
    for (int nt = 0; nt < 8; ++nt) mx = fmaxf(mx, s[nt][r]);
    mx = fmaxf(mx, __shfl_xor(mx, 1)); mx = fmaxf(mx, __shfl_xor(mx, 2));
    mx = fmaxf(mx, __shfl_xor(mx, 4)); mx = fmaxf(mx, __shfl_xor(mx, 8));
    mx *= scale;
    float sm = 0.0f;
#pragma unroll
    for (int nt = 0; nt < 8; ++nt) {
      const float e = __expf(s[nt][r] * scale - mx);
      s[nt][r] = e; sm += e;
    }
    sm += __shfl_xor(sm, 1); sm += __shfl_xor(sm, 2);
    sm += __shfl_xor(sm, 4); sm += __shfl_xor(sm, 8);
    const float inv = 1.0f / sm;
    const int q = m0 + quad * 4 + r;
#pragma unroll
    for (int nt = 0; nt < 8; ++nt) {
      const int k = nt * 16 + lc;
      lP[(k >> 5) * 4096 + ((k >> 3) & 3) * 1024 + q * 8 + (k & 7)] = f2bf(s[nt][r] * inv);
    }
  }
  __syncthreads();

  bf16x8 ap[4];
#pragma unroll
  for (int kc2 = 0; kc2 < 4; ++kc2)
    ap[kc2] = *(const bf16x8*)&lP[kc2 * 4096 + quad * 1024 + (m0 + lc) * 8];

  f32x4 o[16];
#pragma unroll
  for (int nt = 0; nt < 16; ++nt) o[nt] = fz;

  for (int hk = 0; hk < 2; ++hk) {
    if (hk) __syncthreads();
#pragma unroll
    for (int jj = 0; jj < 4; ++jj) {
      const int i = w * 4 + jj;
      const int kc2l = i >> 4, cb = (i >> 2) & 3, db = (i & 3) * 64;
      gl_lds16(Vb + (db + lane) * 128 + (hk * 2 + kc2l) * 32 + cb * 8,
               &lKV[kc2l * 8192 + cb * 2048 + db * 8]);
    }
    __syncthreads();
#pragma unroll
    for (int nt = 0; nt < 16; ++nt)
#pragma unroll
      for (int kc2l = 0; kc2l < 2; ++kc2l) {
        const bf16x8 bfr = *(const bf16x8*)&lKV[kc2l * 8192 + quad * 2048 + (nt * 16 + lc) * 8];
        o[nt] = __builtin_amdgcn_mfma_f32_16x16x32_bf16(ap[hk * 2 + kc2l], bfr, o[nt], 0, 0, 0);
      }
  }

  u16* Ob = Obuf + bb * 262144 + h * 32768;   // == Qb slab; own rows already in aq
#pragma unroll
  for (int nt = 0; nt < 16; ++nt)
#pragma unroll
    for (int r = 0; r < 4; ++r) {
      const int q = m0 + quad * 4 + r;
      Ob[q * 256 + nt * 16 + lc] = f2bf(o[nt][r]);
    }
}

// ---------------- 64x128-tile GEMM (4 waves x 32 cols), optional split-K ----------------
// mode 0: raw fp32 partial store to out + kz*3932160 (Wo split-K path).
// mode 1: bias + bf16 residual epilogue -> fp32 out (FF path, gridDim.z == 1).
__global__ __launch_bounds__(256) void gemm64_kernel(
    const u16* __restrict__ A, const u16* __restrict__ BT, const float* __restrict__ bias,
    const u16* __restrict__ residb, float* __restrict__ out, int Ktot, int lda, int mode)
{
  __shared__ u16 lA[2048];    // [kb 0..3][row 0..63][8]
  __shared__ u16 lB[4096];    // [kb 0..3][half 0..1][col 0..63][8]
  const int t = threadIdx.x;
  const int w = t >> 6, lane = t & 63, quad = lane >> 4, lc = lane & 15;
  const int tn = blockIdx.x, bb = blockIdx.y, kz = blockIdx.z;
  const int kslice = Ktot / gridDim.z;
  const int k0 = kz * kslice;
  const u16* A0 = A + bb * 64 * lda + k0;
  const u16* BT0 = BT + tn * 128 * Ktot + k0;

  const f32x4 fz = {0.f, 0.f, 0.f, 0.f};
  f32x4 acc[4][2];
#pragma unroll
  for (int i = 0; i < 4; ++i) { acc[i][0] = fz; acc[i][1] = fz; }

  const int nck = kslice >> 5;
  for (int ck = 0; ck < nck; ++ck) {
    __syncthreads();
    const int koff = ck * 32 + w * 8;
    gl_lds16(A0 + lane * lda + koff,          &lA[w * 512]);
    gl_lds16(BT0 + lane * Ktot + koff,        &lB[w * 1024]);
    gl_lds16(BT0 + (64 + lane) * Ktot + koff, &lB[w * 1024 + 512]);
    __syncthreads();
    bf16x8 af[4], bfg[2];
#pragma unroll
    for (int mi = 0; mi < 4; ++mi)
      af[mi] = *(const bf16x8*)&lA[quad * 512 + (mi * 16 + lc) * 8];
#pragma unroll
    for (int ni = 0; ni < 2; ++ni) {
      const int cl = w * 32 + ni * 16 + lc;      // 0..127 within tile
      bfg[ni] = *(const bf16x8*)&lB[quad * 1024 + (cl >> 6) * 512 + (cl & 63) * 8];
    }
#pragma unroll
    for (int mi = 0; mi < 4; ++mi)
#pragma unroll
      for (int ni = 0; ni < 2; ++ni)
        acc[mi][ni] = __builtin_amdgcn_mfma_f32_16x16x32_bf16(af[mi], bfg[ni], acc[mi][ni], 0, 0, 0);
  }

  if (mode == 0) {
    float* O = out + kz * 3932160 + bb * 64 * 256;
#pragma unroll
    for (int mi = 0; mi < 4; ++mi)
#pragma unroll
      for (int ni = 0; ni < 2; ++ni) {
        const int cg = tn * 128 + w * 32 + ni * 16 + lc;
#pragma unroll
        for (int r = 0; r < 4; ++r)
          O[(mi * 16 + quad * 4 + r) * 256 + cg] = acc[mi][ni][r];
      }
  } else {
#pragma unroll
    for (int mi = 0; mi < 4; ++mi)
#pragma unroll
      for (int ni = 0; ni < 2; ++ni) {
        const int cg = tn * 128 + w * 32 + ni * 16 + lc;
        const float bi = bias[cg];
#pragma unroll
        for (int r = 0; r < 4; ++r) {
          const int rl = mi * 16 + quad * 4 + r;
          const float res = bf2f(residb[(bb * 64 + rl) * 256 + cg]);
          out[(bb * 64 + rl) * 256 + cg] = acc[mi][ni][r] + bi + res;
        }
      }
  }
}

// ---------------- split-K reduce: tmp1 = sum(4 partials) + bias + fp32 value resid ----------------
// 3840 blocks x 256 thr x 4 elems == 3,932,160 floats (15360 rows x 256 cols).
__global__ __launch_bounds__(256) void reduce_kernel(
    const float* __restrict__ part, const float* __restrict__ bias,
    const float* __restrict__ value, float* __restrict__ out)
{
  const int e = (blockIdx.x * 256 + threadIdx.x) * 4;
  const int row = e >> 8, col = e & 255;
  const int bb = row >> 7, rl = row & 127, b = bb / 15, n = bb % 15;
  f32x4 s = *(const f32x4*)(part + e);
#pragma unroll
  for (int p = 1; p < 4; ++p) {
    const f32x4 v = *(const f32x4*)(part + p * 3932160 + e);
#pragma unroll
    for (int i = 0; i < 4; ++i) s[i] += v[i];
  }
  const f32x4 bi = *(const f32x4*)(bias + col);
  const f32x4 rv = *(const f32x4*)(value + (b * 1024 + n * 64 + rl) * 256 + col);
#pragma unroll
  for (int i = 0; i < 4; ++i) s[i] += bi[i] + rv[i];
  *(f32x4*)(out + e) = s;
}

// ---------------- layernorm (one wave per 256-wide row) ----------------
__global__ __launch_bounds__(256) void ln_kernel(
    const float* __restrict__ src, const float* __restrict__ gam, const float* __restrict__ bet,
    u16* __restrict__ dstb, float* __restrict__ dstf, int mode)
{
  const int t = threadIdx.x, w = t >> 6, lane = t & 63;
  const int row = blockIdx.x * 4 + w;
  const f32x4 v = *(const f32x4*)(src + row * 256 + lane * 4);
  float sum = v[0] + v[1] + v[2] + v[3];
  float sq = v[0] * v[0] + v[1] * v[1] + v[2] * v[2] + v[3] * v[3];
#pragma unroll
  for (int m = 1; m < 64; m <<= 1) { sum += __shfl_xor(sum, m); sq += __shfl_xor(sq, m); }
  const float mean = sum * (1.0f / 256.0f);
  const float rs = rsqrtf(sq * (1.0f / 256.0f) - mean * mean + 1e-5f);
  const f32x4 g4 = *(const f32x4*)(gam + lane * 4);
  const f32x4 b4 = *(const f32x4*)(bet + lane * 4);
  f32x4 o;
#pragma unroll
  for (int i = 0; i < 4; ++i)
    o[i] = (v[i] - mean) * rs * g4[i] + b4[i];
  if (mode == 0) {
    u16x4 ob;
#pragma unroll
    for (int i = 0; i < 4; ++i) ob[i] = f2bf(o[i]);
    *(u16x4*)(dstb + row * 256 + lane * 4) = ob;
  } else {
    const int bbq = row >> 7, r = row & 127, b = bbq / 15, n = bbq % 15;
    const bool valid = (n == 0) ? (r < 96) : ((n == 14) ? (r >= 32) : (r >= 32 && r < 96));
    if (valid)
      *(f32x4*)(dstf + ((b << 10) + n * 64 + r) * 256 + lane * 4) = o;
  }
}

extern "C" void kernel_launch(void* const* d_in, const int* in_sizes, int n_in,
                              void* d_out, int out_size, void* d_ws, size_t ws_size,
                              hipStream_t stream) {
  (void)in_sizes; (void)n_in; (void)out_size; (void)ws_size;
  const float* query = (const float*)d_in[0];
  const float* key   = (const float*)d_in[1];
  const float* value = (const float*)d_in[2];
  const float* Wq  = (const float*)d_in[3];
  const float* bq  = (const float*)d_in[4];
  const float* Wk  = (const float*)d_in[5];
  const float* bk  = (const float*)d_in[6];
  const float* Wv  = (const float*)d_in[7];
  const float* bv  = (const float*)d_in[8];
  const float* Wo  = (const float*)d_in[9];
  const float* bo  = (const float*)d_in[10];
  const float* g1  = (const float*)d_in[11];
  const float* b1  = (const float*)d_in[12];
  const float* Wff = (const float*)d_in[13];
  const float* bff = (const float*)d_in[14];
  const float* g2  = (const float*)d_in[15];
  const float* b2  = (const float*)d_in[16];

  // Phase-ordered layout, peak 205,651,968 B (round-2 validated footprint):
  u16* ws   = (u16*)d_ws;
  u16* WT   = ws;                    // 2,162,688 u16 (WqT,WkT,WvT,WoT,WffT)
  u16* qb   = ws + 2162688;          // 2,097,152 u16 each
  u16* kb   = qb + 2097152;
  u16* vb   = kb + 2097152;
  u16* S1   = vb + 2097152;          // slab 31,457,280 u16: Pv -> Pq -> Obuf
  u16* S2   = S1 + 31457280;         // slab: VT -> Wo split-K partials (4 x 3,932,160 f32) -> tmp2
  u16* S3   = S2 + 31457280;         // slab: Pk -> tmp1/xbuf
  float* part = (float*)S2;          // 4 x 3,932,160 f32 == exactly one slab
  float* tmp1 = (float*)S3;          // 3,932,160 f32 (Pk dead after attn)
  u16* xbuf   = S3 + 7864320;
  float* tmp2 = (float*)S2;          // (partials dead after reduce)

  convert_kernel<<<dim3(2048, 3), 256, 0, stream>>>(query, key, value, qb, kb, vb);
  transpose_kernel<<<dim3(2048, 5), 256, 0, stream>>>(Wq, Wk, Wv, Wo, Wff, WT);
  // V projection first -> S1, transpose into S2, then Q/K reuse S1/S3.
  proj_kernel<<<dim3(16, 120, 1), 256, 0, stream>>>(qb, kb, vb, WT, bq, bk, bv, S1, S3, S1, 2);
  vtrans_kernel<<<dim3(8, 960), 256, 0, stream>>>(S1, S2);
  proj_kernel<<<dim3(16, 120, 2), 256, 0, stream>>>(qb, kb, vb, WT, bq, bk, bv, S1, S3, S1, 0);
  attn_kernel<<<dim3(8, 120), 512, 0, stream>>>(S1, S3, S2, S1);
  // Wo GEMM: 64-row tiles, split-K=4 -> partials in S2, then reduce (+bias+value resid).
  gemm64_kernel<<<dim3(2, 240, 4), 256, 0, stream>>>(S1, WT + 1572864, nullptr, nullptr, part, 2048, 2048, 0);
  reduce_kernel<<<3840, 256, 0, stream>>>(part, bo, value, tmp1);
  ln_kernel<<<3840, 256, 0, stream>>>(tmp1, g1, b1, xbuf, nullptr, 0);
  // FF GEMM: 64-row tiles, fused bias + residual epilogue.
  gemm64_kernel<<<dim3(2, 240, 1), 256, 0, stream>>>(xbuf, WT + 2097152, bff, xbuf, tmp2, 256, 256, 1);
  ln_kernel<<<3840, 256, 0, stream>>>(tmp2, g2, b2, nullptr, (float*)d_out, 1);
}

// Round 11
// 329.186 us; speedup vs baseline: 1.3904x; 1.3851x over previous
//
#include <hip/hip_runtime.h>
#include <cstdint>

typedef unsigned short u16;
typedef __attribute__((ext_vector_type(8))) short bf16x8;
typedef __attribute__((ext_vector_type(4))) float f32x4;
typedef __attribute__((ext_vector_type(4))) unsigned short u16x4;

#define AS_G __attribute__((address_space(1)))
#define AS_L __attribute__((address_space(3)))

__device__ __forceinline__ void gl_lds16(const u16* g, u16* l) {
  // async global->LDS, 16B/lane; LDS dest = wave-uniform base + lane*16
  __builtin_amdgcn_global_load_lds((const AS_G unsigned int*)g, (AS_L unsigned int*)l, 16, 0, 0);
}
__device__ __forceinline__ float bf2f(u16 u) {
  union { unsigned int i; float f; } v; v.i = ((unsigned int)u) << 16; return v.f;
}
__device__ __forceinline__ u16 f2bf(float f) {
  union { float f; unsigned int i; } v; v.f = f;
  unsigned int x = v.i;
  return (u16)((x + 0x7fffu + ((x >> 16) & 1u)) >> 16);  // RNE
}

// ---------------- fp32 -> bf16 convert of q/k/v ----------------
__global__ __launch_bounds__(256) void convert_kernel(
    const float* __restrict__ q, const float* __restrict__ k, const float* __restrict__ v,
    u16* __restrict__ qb, u16* __restrict__ kb, u16* __restrict__ vb)
{
  const int id = blockIdx.y;
  const float* s = (id == 0) ? q : (id == 1) ? k : v;
  u16* d = (id == 0) ? qb : (id == 1) ? kb : vb;
  const int o = (blockIdx.x * 256 + threadIdx.x) * 4;
  const f32x4 x = *(const f32x4*)(s + o);
  u16x4 y;
#pragma unroll
  for (int i = 0; i < 4; ++i) y[i] = f2bf(x[i]);
  *(u16x4*)(d + o) = y;
}

// ---------------- weight pre-transpose (fp32 src -> bf16 dst) ----------------
__global__ __launch_bounds__(256) void transpose_kernel(
    const float* __restrict__ s0, const float* __restrict__ s1, const float* __restrict__ s2,
    const float* __restrict__ s3, const float* __restrict__ s4, u16* __restrict__ wdst)
{
  const int id = blockIdx.y;
  const float* src; u16* dst; int rb, total;
  switch (id) {
    case 0:  src = s0; dst = wdst;           rb = 8;  total = 524288; break;
    case 1:  src = s1; dst = wdst + 524288;  rb = 8;  total = 524288; break;
    case 2:  src = s2; dst = wdst + 1048576; rb = 8;  total = 524288; break;
    case 3:  src = s3; dst = wdst + 1572864; rb = 11; total = 524288; break;
    default: src = s4; dst = wdst + 2097152; rb = 8;  total = 65536;  break;
  }
  const int o = blockIdx.x * 256 + threadIdx.x;
  if (o >= total) return;
  const int C_ = total >> rb;
  const int c = o >> rb, r = o & ((1 << rb) - 1);
  dst[o] = f2bf(src[r * C_ + c]);
}

// ---------------- QKV projection on the UNGATHERED 8192 rows ----------------
// proj commutes with the row gather, so project original rows once (25.8 vs
// 48.3 GFLOP). Raw-reshape head semantics (h = row>>4) are honored downstream
// by slab indexing, so the epilogue is plain row-major for all of q/k/v.
// 128x128 tile, 4 waves, R6-proven 8-chunk staging + coalesced LDS epilogue.
__global__ __launch_bounds__(256) void proj_kernel(
    const u16* __restrict__ qb, const u16* __restrict__ kb, const u16* __restrict__ vb,
    const u16* __restrict__ wts, const float* __restrict__ bq, const float* __restrict__ bk,
    const float* __restrict__ bv, u16* __restrict__ Pq, u16* __restrict__ Pk,
    u16* __restrict__ Pv)
{
  __shared__ u16 lds[17408];            // K-loop: [0:4096)=A, [4096:8192)=B; epilogue: 128x136
  const int t = threadIdx.x;
  const int w = t >> 6, lane = t & 63, quad = lane >> 4, lc = lane & 15;
  const int wy = w >> 1, wx = w & 1;
  const int tn = blockIdx.x, by = blockIdx.y, z = blockIdx.z;
  const u16* A0 = ((z == 0) ? qb : (z == 1) ? kb : vb) + by * 32768;   // 128 rows x 256
  const u16* BT = wts + z * 524288 + tn * 128 * 256;

  const f32x4 fz = {0.f, 0.f, 0.f, 0.f};
  f32x4 acc[4][4];
#pragma unroll
  for (int i = 0; i < 4; ++i)
#pragma unroll
    for (int j = 0; j < 4; ++j) acc[i][j] = fz;

  for (int ck = 0; ck < 8; ++ck) {
    __syncthreads();
    const int koff = ck * 32 + w * 8;
    gl_lds16(A0 + lane * 256 + koff,        &lds[w * 1024]);
    gl_lds16(A0 + (64 + lane) * 256 + koff, &lds[w * 1024 + 512]);
    gl_lds16(BT + lane * 256 + koff,        &lds[4096 + w * 1024]);
    gl_lds16(BT + (64 + lane) * 256 + koff, &lds[4096 + w * 1024 + 512]);
    __syncthreads();
    bf16x8 af[4], bfg[4];
#pragma unroll
    for (int mi = 0; mi < 4; ++mi)
      af[mi] = *(const bf16x8*)&lds[quad * 1024 + (wy * 64 + mi * 16 + lc) * 8];
#pragma unroll
    for (int ni = 0; ni < 4; ++ni)
      bfg[ni] = *(const bf16x8*)&lds[4096 + quad * 1024 + (wx * 64 + ni * 16 + lc) * 8];
#pragma unroll
    for (int mi = 0; mi < 4; ++mi)
#pragma unroll
      for (int ni = 0; ni < 4; ++ni)
        acc[mi][ni] = __builtin_amdgcn_mfma_f32_16x16x32_bf16(af[mi], bfg[ni], acc[mi][ni], 0, 0, 0);
  }

  const float* bias = (z == 0) ? bq : (z == 1) ? bk : bv;
  u16* P = ((z == 0) ? Pq : (z == 1) ? Pk : Pv) + by * 262144;

  __syncthreads();                       // staging reads complete; reuse LDS
#pragma unroll
  for (int mi = 0; mi < 4; ++mi)
#pragma unroll
    for (int ni = 0; ni < 4; ++ni) {
      const int col = wx * 64 + ni * 16 + lc;
      const float bi = bias[tn * 128 + col];
#pragma unroll
      for (int r = 0; r < 4; ++r) {
        const int row = wy * 64 + mi * 16 + quad * 4 + r;
        lds[row * 136 + col] = f2bf(acc[mi][ni][r] + bi);
      }
    }
  __syncthreads();
#pragma unroll
  for (int p = 0; p < 8; ++p) {          // 256B-contiguous row segments, 16B/lane
    const int e = p * 2048 + t * 8;
    const int row = e >> 7, col0 = e & 127;
    *(bf16x8*)(P + row * 2048 + tn * 128 + col0) = *(const bf16x8*)&lds[row * 136 + col0];
  }
}

// ---------------- Pv group-slab transpose (coalesced both sides) ----------------
// Group g = original_row/16: slab Pv+g*32768 viewed [q'=128][d=256] (raw
// reshape) -> VT+g*32768 as [d=256][q'=128]. Identical body to the proven
// vtrans; only 512 groups now.
__global__ __launch_bounds__(256) void vtrans_kernel(
    const u16* __restrict__ Pv, u16* __restrict__ VT)
{
  __shared__ u16 lT[4096];
  const int t = threadIdx.x;
  const int tile = blockIdx.x;          // 0..7
  const int g = blockIdx.y;             // 0..511
  const int q0 = (tile & 1) * 64, d0 = (tile >> 1) * 64;
  const u16* src = Pv + g * 32768;      // [q'=128][d=256]
  u16* dst = VT + g * 32768;            // [d=256][q'=128]
#pragma unroll
  for (int it = 0; it < 2; ++it) {
    const int e = it * 2048 + t * 8;
    const int lq = e >> 6, ld0 = e & 63;
    const bf16x8 v = *(const bf16x8*)(src + (q0 + lq) * 256 + d0 + ld0);
    const int kb = ((ld0 >> 3) + lq + (lq >> 3)) & 7;
    *(bf16x8*)&lT[lq * 64 + kb * 8] = v;
  }
  __syncthreads();
#pragma unroll
  for (int it = 0; it < 2; ++it) {
    const int e = it * 2048 + t * 8;
    const int ld = e >> 6, lq0 = e & 63;
    bf16x8 v;
#pragma unroll
    for (int i = 0; i < 8; ++i) {
      const int lq = lq0 + i;
      const int kb = ((ld >> 3) + lq + (lq >> 3)) & 7;
      v[i] = (short)lT[lq * 64 + kb * 8 + (ld & 7)];
    }
    *(bf16x8*)(dst + (d0 + ld) * 128 + q0 + lq0) = v;
  }
}

// ---------------- attention per (block, head) ----------------
// Raw-reshape head semantics: unit (b,n,h) = contiguous P rows r0..r0+16
// (r0 = b*1024+64n+16h) viewed [q=128][d=256]; VT group g = b*64+4n+h.
// Body identical to the R6-passing kernel; only base pointers changed.
__global__ __launch_bounds__(512) void attn_kernel(
    const u16* __restrict__ Pq, const u16* __restrict__ Pk,
    const u16* __restrict__ VT, u16* __restrict__ Obuf)
{
  __shared__ u16 lKV[16384];
  __shared__ u16 lP[16384];
  const int t = threadIdx.x;
  const int w = t >> 6, lane = t & 63, quad = lane >> 4, lc = lane & 15;
  const int h = blockIdx.x, bb = blockIdx.y;
  const int b = bb / 15, n = bb % 15;
  const int m0 = w * 16;
  const int r0 = b * 1024 + n * 64 + h * 16;
  const u16* Qb = Pq + r0 * 2048;
  const u16* Kb = Pk + r0 * 2048;
  const u16* Vb = VT + (b * 64 + n * 4 + h) * 32768;
  const f32x4 fz = {0.f, 0.f, 0.f, 0.f};

  bf16x8 aq[8];
#pragma unroll
  for (int kc = 0; kc < 8; ++kc)
    aq[kc] = *(const bf16x8*)(Qb + (m0 + lc) * 256 + kc * 32 + quad * 8);

  f32x4 s[8];
  for (int hk = 0; hk < 2; ++hk) {
    __syncthreads();
#pragma unroll
    for (int jj = 0; jj < 4; ++jj)
      gl_lds16(Kb + (hk * 64 + lane) * 256 + w * 32 + jj * 8, &lKV[w * 2048 + jj * 512]);
    __syncthreads();
#pragma unroll
    for (int ntl = 0; ntl < 4; ++ntl) {
      const int nt = hk * 4 + ntl;
      s[nt] = fz;
#pragma unroll
      for (int kc = 0; kc < 8; ++kc) {
        const bf16x8 bfr = *(const bf16x8*)&lKV[kc * 2048 + quad * 512 + (ntl * 16 + lc) * 8];
        s[nt] = __builtin_amdgcn_mfma_f32_16x16x32_bf16(aq[kc], bfr, s[nt], 0, 0, 0);
      }
    }
  }

  const float scale = 0.0625f;
#pragma unroll
  for (int r = 0; r < 4; ++r) {
    float mx = -3.0e38f;
#pragma unroll
    for (int nt = 0; nt < 8; ++nt) mx = fmaxf(mx, s[nt][r]);
    mx = fmaxf(mx, __shfl_xor(mx, 1)); mx = fmaxf(mx, __shfl_xor(mx, 2));
    mx = fmaxf(mx, __shfl_xor(mx, 4)); mx = fmaxf(mx, __shfl_xor(mx, 8));
    mx *= scale;
    float sm = 0.0f;
#pragma unroll
    for (int nt = 0; nt < 8; ++nt) {
      const float e = __expf(s[nt][r] * scale - mx);
      s[nt][r] = e; sm += e;
    }
    sm += __shfl_xor(sm, 1); sm += __shfl_xor(sm, 2);
    sm += __shfl_xor(sm, 4); sm += __shfl_xor(sm, 8);
    const float inv = 1.0f / sm;
    const int q = m0 + quad * 4 + r;
#pragma unroll
    for (int nt = 0; nt < 8; ++nt) {
      const int k = nt * 16 + lc;
      lP[(k >> 5) * 4096 + ((k >> 3) & 3) * 1024 + q * 8 + (k & 7)] = f2bf(s[nt][r] * inv);
    }
  }
  __syncthreads();

  bf16x8 ap[4];
#pragma unroll
  for (int kc2 = 0; kc2 < 4; ++kc2)
    ap[kc2] = *(const bf16x8*)&lP[kc2 * 4096 + quad * 1024 + (m0 + lc) * 8];

  f32x4 o[16];
#pragma unroll
  for (int nt = 0; nt < 16; ++nt) o[nt] = fz;

  for (int hk = 0; hk < 2; ++hk) {
    if (hk) __syncthreads();
#pragma unroll
    for (int jj = 0; jj < 4; ++jj) {
      const int i = w * 4 + jj;
      const int kc2l = i >> 4, cb = (i >> 2) & 3, db = (i & 3) * 64;
      gl_lds16(Vb + (db + lane) * 128 + (hk * 2 + kc2l) * 32 + cb * 8,
               &lKV[kc2l * 8192 + cb * 2048 + db * 8]);
    }
    __syncthreads();
#pragma unroll
    for (int nt = 0; nt < 16; ++nt)
#pragma unroll
      for (int kc2l = 0; kc2l < 2; ++kc2l) {
        const bf16x8 bfr = *(const bf16x8*)&lKV[kc2l * 8192 + quad * 2048 + (nt * 16 + lc) * 8];
        o[nt] = __builtin_amdgcn_mfma_f32_16x16x32_bf16(ap[hk * 2 + kc2l], bfr, o[nt], 0, 0, 0);
      }
  }

  u16* Ob = Obuf + bb * 262144 + h * 32768;   // gathered output (separate buffer)
#pragma unroll
  for (int nt = 0; nt < 16; ++nt)
#pragma unroll
    for (int r = 0; r < 4; ++r) {
      const int q = m0 + quad * 4 + r;
      Ob[q * 256 + nt * 16 + lc] = f2bf(o[nt][r]);
    }
}

// ---------------- 64x128-tile GEMM (4 waves x 32 cols), optional split-K ----------------
// mode 0: raw fp32 partial store to out + kz*3932160 (Wo split-K path).
// mode 1: bias + bf16 residual epilogue -> fp32 out (FF path, gridDim.z == 1).
__global__ __launch_bounds__(256) void gemm64_kernel(
    const u16* __restrict__ A, const u16* __restrict__ BT, const float* __restrict__ bias,
    const u16* __restrict__ residb, float* __restrict__ out, int Ktot, int lda, int mode)
{
  __shared__ u16 lA[2048];
  __shared__ u16 lB[4096];
  const int t = threadIdx.x;
  const int w = t >> 6, lane = t & 63, quad = lane >> 4, lc = lane & 15;
  const int tn = blockIdx.x, bb = blockIdx.y, kz = blockIdx.z;
  const int kslice = Ktot / gridDim.z;
  const int k0 = kz * kslice;
  const u16* A0 = A + bb * 64 * lda + k0;
  const u16* BT0 = BT + tn * 128 * Ktot + k0;

  const f32x4 fz = {0.f, 0.f, 0.f, 0.f};
  f32x4 acc[4][2];
#pragma unroll
  for (int i = 0; i < 4; ++i) { acc[i][0] = fz; acc[i][1] = fz; }

  const int nck = kslice >> 5;
  for (int ck = 0; ck < nck; ++ck) {
    __syncthreads();
    const int koff = ck * 32 + w * 8;
    gl_lds16(A0 + lane * lda + koff,          &lA[w * 512]);
    gl_lds16(BT0 + lane * Ktot + koff,        &lB[w * 1024]);
    gl_lds16(BT0 + (64 + lane) * Ktot + koff, &lB[w * 1024 + 512]);
    __syncthreads();
    bf16x8 af[4], bfg[2];
#pragma unroll
    for (int mi = 0; mi < 4; ++mi)
      af[mi] = *(const bf16x8*)&lA[quad * 512 + (mi * 16 + lc) * 8];
#pragma unroll
    for (int ni = 0; ni < 2; ++ni) {
      const int cl = w * 32 + ni * 16 + lc;
      bfg[ni] = *(const bf16x8*)&lB[quad * 1024 + (cl >> 6) * 512 + (cl & 63) * 8];
    }
#pragma unroll
    for (int mi = 0; mi < 4; ++mi)
#pragma unroll
      for (int ni = 0; ni < 2; ++ni)
        acc[mi][ni] = __builtin_amdgcn_mfma_f32_16x16x32_bf16(af[mi], bfg[ni], acc[mi][ni], 0, 0, 0);
  }

  if (mode == 0) {
    float* O = out + kz * 3932160 + bb * 64 * 256;
#pragma unroll
    for (int mi = 0; mi < 4; ++mi)
#pragma unroll
      for (int ni = 0; ni < 2; ++ni) {
        const int cg = tn * 128 + w * 32 + ni * 16 + lc;
#pragma unroll
        for (int r = 0; r < 4; ++r)
          O[(mi * 16 + quad * 4 + r) * 256 + cg] = acc[mi][ni][r];
      }
  } else {
#pragma unroll
    for (int mi = 0; mi < 4; ++mi)
#pragma unroll
      for (int ni = 0; ni < 2; ++ni) {
        const int cg = tn * 128 + w * 32 + ni * 16 + lc;
        const float bi = bias[cg];
#pragma unroll
        for (int r = 0; r < 4; ++r) {
          const int rl = mi * 16 + quad * 4 + r;
          const float res = bf2f(residb[(bb * 64 + rl) * 256 + cg]);
          out[(bb * 64 + rl) * 256 + cg] = acc[mi][ni][r] + bi + res;
        }
      }
  }
}

// ---------------- split-K reduce: tmp1 = sum(4 partials) + bias + fp32 value resid ----------------
// 3840 blocks x 256 thr x 4 elems == 3,932,160 floats (15360 rows x 256 cols).
__global__ __launch_bounds__(256) void reduce_kernel(
    const float* __restrict__ part, const float* __restrict__ bias,
    const float* __restrict__ value, float* __restrict__ out)
{
  const int e = (blockIdx.x * 256 + threadIdx.x) * 4;
  const int row = e >> 8, col = e & 255;
  const int bb = row >> 7, rl = row & 127, b = bb / 15, n = bb % 15;
  f32x4 s = *(const f32x4*)(part + e);
#pragma unroll
  for (int p = 1; p < 4; ++p) {
    const f32x4 v = *(const f32x4*)(part + p * 3932160 + e);
#pragma unroll
    for (int i = 0; i < 4; ++i) s[i] += v[i];
  }
  const f32x4 bi = *(const f32x4*)(bias + col);
  const f32x4 rv = *(const f32x4*)(value + (b * 1024 + n * 64 + rl) * 256 + col);
#pragma unroll
  for (int i = 0; i < 4; ++i) s[i] += bi[i] + rv[i];
  *(f32x4*)(out + e) = s;
}

// ---------------- layernorm (one wave per 256-wide row) ----------------
__global__ __launch_bounds__(256) void ln_kernel(
    const float* __restrict__ src, const float* __restrict__ gam, const float* __restrict__ bet,
    u16* __restrict__ dstb, float* __restrict__ dstf, int mode)
{
  const int t = threadIdx.x, w = t >> 6, lane = t & 63;
  const int row = blockIdx.x * 4 + w;
  const f32x4 v = *(const f32x4*)(src + row * 256 + lane * 4);
  float sum = v[0] + v[1] + v[2] + v[3];
  float sq = v[0] * v[0] + v[1] * v[1] + v[2] * v[2] + v[3] * v[3];
#pragma unroll
  for (int m = 1; m < 64; m <<= 1) { sum += __shfl_xor(sum, m); sq += __shfl_xor(sq, m); }
  const float mean = sum * (1.0f / 256.0f);
  const float rs = rsqrtf(sq * (1.0f / 256.0f) - mean * mean + 1e-5f);
  const f32x4 g4 = *(const f32x4*)(gam + lane * 4);
  const f32x4 b4 = *(const f32x4*)(bet + lane * 4);
  f32x4 o;
#pragma unroll
  for (int i = 0; i < 4; ++i)
    o[i] = (v[i] - mean) * rs * g4[i] + b4[i];
  if (mode == 0) {
    u16x4 ob;
#pragma unroll
    for (int i = 0; i < 4; ++i) ob[i] = f2bf(o[i]);
    *(u16x4*)(dstb + row * 256 + lane * 4) = ob;
  } else {
    const int bbq = row >> 7, r = row & 127, b = bbq / 15, n = bbq % 15;
    const bool valid = (n == 0) ? (r < 96) : ((n == 14) ? (r >= 32) : (r >= 32 && r < 96));
    if (valid)
      *(f32x4*)(dstf + ((b << 10) + n * 64 + r) * 256 + lane * 4) = o;
  }
}

extern "C" void kernel_launch(void* const* d_in, const int* in_sizes, int n_in,
                              void* d_out, int out_size, void* d_ws, size_t ws_size,
                              hipStream_t stream) {
  (void)in_sizes; (void)n_in; (void)out_size; (void)ws_size;
  const float* query = (const float*)d_in[0];
  const float* key   = (const float*)d_in[1];
  const float* value = (const float*)d_in[2];
  const float* Wq  = (const float*)d_in[3];
  const float* bq  = (const float*)d_in[4];
  const float* Wk  = (const float*)d_in[5];
  const float* bk  = (const float*)d_in[6];
  const float* Wv  = (const float*)d_in[7];
  const float* bv  = (const float*)d_in[8];
  const float* Wo  = (const float*)d_in[9];
  const float* bo  = (const float*)d_in[10];
  const float* g1  = (const float*)d_in[11];
  const float* b1  = (const float*)d_in[12];
  const float* Wff = (const float*)d_in[13];
  const float* bff = (const float*)d_in[14];
  const float* g2  = (const float*)d_in[15];
  const float* b2  = (const float*)d_in[16];

  // Ungathered-projection layout; peak 180,486,144 B:
  u16* ws  = (u16*)d_ws;
  u16* WT  = ws;                      // [0, 2162688)
  u16* qb  = ws + 2162688;            // 2,097,152 each (8192x256 bf16)
  u16* kb  = ws + 4259840;
  u16* vb  = ws + 6356992;
  u16* Pq  = ws + 8454144;            // 16,777,216 each (8192x2048 bf16)
  u16* Pk  = ws + 25231360;
  u16* VT  = ws + 42008576;           // 512 groups x [d=256][q'=128]
  u16* Obuf = ws + 58785792;          // 31,457,280 (gathered 15360x2048)
  u16* Pv  = Obuf;                    // first 16,777,216 of Obuf (dead before attn writes O)
  float* part = (float*)(ws + 8454144);   // 15,728,640 f32 over Pq+Pk (dead after attn)
  float* tmp1 = (float*)(ws + 42008576);  // 3,932,160 f32 over VT (dead after attn)
  u16* xbuf   = ws + 49872896;            // 3,932,160 u16, still within VT region
  float* tmp2 = (float*)(ws + 58785792);  // over Obuf (dead after Wo gemm)

  convert_kernel<<<dim3(2048, 3), 256, 0, stream>>>(query, key, value, qb, kb, vb);
  transpose_kernel<<<dim3(2048, 5), 256, 0, stream>>>(Wq, Wk, Wv, Wo, Wff, WT);
  // Single proj pass over q/k/v on the original 8192 rows.
  proj_kernel<<<dim3(16, 64, 3), 256, 0, stream>>>(qb, kb, vb, WT, bq, bk, bv, Pq, Pk, Pv);
  vtrans_kernel<<<dim3(8, 512), 256, 0, stream>>>(Pv, VT);
  attn_kernel<<<dim3(8, 120), 512, 0, stream>>>(Pq, Pk, VT, Obuf);
  // Wo GEMM: 64-row tiles, split-K=4 -> partials, then reduce (+bias+value resid).
  gemm64_kernel<<<dim3(2, 240, 4), 256, 0, stream>>>(Obuf, WT + 1572864, nullptr, nullptr, part, 2048, 2048, 0);
  reduce_kernel<<<3840, 256, 0, stream>>>(part, bo, value, tmp1);
  ln_kernel<<<3840, 256, 0, stream>>>(tmp1, g1, b1, xbuf, nullptr, 0);
  // FF GEMM: 64-row tiles, fused bias + residual epilogue.
  gemm64_kernel<<<dim3(2, 240, 1), 256, 0, stream>>>(xbuf, WT + 2097152, bff, xbuf, tmp2, 256, 256, 1);
  ln_kernel<<<3840, 256, 0, stream>>>(tmp2, g2, b2, nullptr, (float*)d_out, 1);
}